// Round 8
// baseline (181.908 us; speedup 1.0000x reference)
//
#include <hip/hip_runtime.h>
#include <math.h>

// Problem constants (reference setup_inputs: B=32, H=80, W=120, A=9)
#define NA     9
#define HH     80
#define WWID   120
#define HWSZ   (HH * WWID)        // 9600
#define NANC   (HWSZ * NA)        // 86400 anchors per image
#define NANC4  (NANC / 4)         // 21600 float4 groups
#define PRE_NMS 100
#define NMS_THRESH 0.3f
#define MIN_SIZE 8.0f
#define STRIDE_F 16.0f
#define NBIN   4096               // 12-bit histogram of ordered-f32
#define CAP    2048               // per-batch candidate cap (expected ~183)
#define NCH    22                 // chunks of 1024 float4-groups (22*1024 >= 21600)

// Anchor geometry: all 9 anchors share center (8,8); widths/heights exact
// (verified against _generate_anchors(16,(0.5,1,2),(8,16,32))).
__constant__ float c_aw[NA] = {184.f, 368.f, 736.f, 128.f, 256.f, 512.f,  88.f, 176.f, 352.f};
__constant__ float c_ah[NA] = { 96.f, 192.f, 384.f, 128.f, 256.f, 512.f, 176.f, 352.f, 704.f};

// ---------------------------------------------------------------- decode ----
__device__ inline void decode_box(int n, float4 d, float imgW, float imgH,
                                  float& x1, float& y1, float& x2, float& y2) {
    int a = n % NA;
    int s = n / NA;
    int yy = s / WWID;
    int xx = s - yy * WWID;
    float aw = c_aw[a], ah = c_ah[a];
    float acx = 8.0f + STRIDE_F * (float)xx;
    float acy = 8.0f + STRIDE_F * (float)yy;
    float pcx = d.x * aw + acx;
    float pcy = d.y * ah + acy;
    float pw  = expf(d.z) * aw;
    float ph  = expf(d.w) * ah;
    x1 = pcx - 0.5f * pw;
    y1 = pcy - 0.5f * ph;
    x2 = pcx + 0.5f * pw;
    y2 = pcy + 0.5f * ph;
    float mx = imgW - 1.0f, my = imgH - 1.0f;
    x1 = fminf(fmaxf(x1, 0.0f), mx);
    x2 = fminf(fmaxf(x2, 0.0f), mx);
    y1 = fminf(fmaxf(y1, 0.0f), my);
    y2 = fminf(fmaxf(y2, 0.0f), my);
}

// order-preserving uint mapping (monotonic for all floats incl +-inf)
__device__ inline unsigned int f32_ord(float v) {
    unsigned int u = __float_as_uint(v);
    return (u & 0x80000000u) ? ~u : (u | 0x80000000u);
}
__device__ inline float ord_f32(unsigned int ov) {
    unsigned int u = (ov & 0x80000000u) ? (ov ^ 0x80000000u) : ~ov;
    return __uint_as_float(u);
}

// ---------------- K0: batch-0 size mask + zero {ghist, tArr, cntArr, done} --
// mask stored in score-memory order m = a*HWSZ + s so later reads coalesce.
__global__ void k_mask(const float* __restrict__ delta,
                       const float* __restrict__ img,
                       unsigned char* __restrict__ mask,
                       unsigned int* __restrict__ zero_base, int nzero) {
    int gid = blockIdx.x * blockDim.x + threadIdx.x;
    for (int i = gid; i < nzero; i += gridDim.x * blockDim.x) zero_base[i] = 0u;
    if (gid >= NANC) return;
    float4 d = reinterpret_cast<const float4*>(delta)[gid];  // batch 0, contiguous
    float imgH = img[0], imgW = img[1];
    float x1, y1, x2, y2;
    decode_box(gid, d, imgW, imgH, x1, y1, x2, y2);
    float ws = x2 - x1 + 1.0f;
    float hs = y2 - y1 + 1.0f;
    int a = gid % NA;
    int s = gid / NA;
    mask[a * HWSZ + s] = (ws >= MIN_SIZE && hs >= MIN_SIZE) ? 1 : 0;
}

// ------ K1: per-(chunk,batch) dual-LDS histogram -> global accumulate; ------
// the last-finishing block of each batch computes the threshold bin T:
// T = max bin with count(bins >= T) >= 100  => global top-100 all in bins >= T.
__global__ __launch_bounds__(256)
void k_hist(const float* __restrict__ score,
            const unsigned char* __restrict__ mask,
            unsigned int* __restrict__ ghist,
            unsigned int* __restrict__ done,
            unsigned int* __restrict__ tArr) {
    __shared__ unsigned int lh0[NBIN];
    __shared__ unsigned int lh1[NBIN];
    __shared__ unsigned int part[256];
    __shared__ int lastFlag;
    __shared__ int best;
    int chunk = blockIdx.x, b = blockIdx.y, tid = threadIdx.x;
    for (int i = tid; i < NBIN; i += 256) { lh0[i] = 0u; lh1[i] = 0u; }
    if (tid == 0) best = 0;
    __syncthreads();

    // waves 0-1 -> lh0, waves 2-3 -> lh1 (halves same-address contention)
    unsigned int* lh = (tid < 128) ? lh0 : lh1;

    const float4* fg = reinterpret_cast<const float4*>(
        score + (size_t)b * (2 * NA * HWSZ) + (size_t)NA * HWSZ);
    const uchar4* mk = reinterpret_cast<const uchar4*>(mask);
    #pragma unroll
    for (int it = 0; it < 4; ++it) {
        int q = chunk * 1024 + it * 256 + tid;
        if (q < NANC4) {
            float4 v = fg[q];
            uchar4 m = mk[q];
            float a0 = m.x ? v.x : -INFINITY;
            float a1 = m.y ? v.y : -INFINITY;
            float a2 = m.z ? v.z : -INFINITY;
            float a3 = m.w ? v.w : -INFINITY;
            atomicAdd(&lh[f32_ord(a0) >> 20], 1u);
            atomicAdd(&lh[f32_ord(a1) >> 20], 1u);
            atomicAdd(&lh[f32_ord(a2) >> 20], 1u);
            atomicAdd(&lh[f32_ord(a3) >> 20], 1u);
        }
    }
    __syncthreads();
    unsigned int* gh = ghist + (size_t)b * NBIN;
    for (int i = tid; i < NBIN; i += 256) {
        unsigned c = lh0[i] + lh1[i];
        if (c) atomicAdd(&gh[i], c);   // zero-skip: ~200-400 nonzero bins/block
    }
    __syncthreads();   // compiler emits s_waitcnt vmcnt(0) before s_barrier:
                       // all lanes' gh atomics are complete at coherence point

    // last-block-per-batch does the suffix-scan threshold
    if (tid == 0) {
        __threadfence();               // belt-and-braces release
        unsigned old = atomicAdd(&done[b], 1u);
        lastFlag = (old == NCH - 1);
    }
    __syncthreads();
    if (!lastFlag) return;
    __threadfence();                   // acquire side

    // read bins with device-scope atomic reads (cross-XCD-coherent)
    unsigned g[16];
    unsigned ssum = 0;
    unsigned int* h = gh + tid * 16;
    #pragma unroll
    for (int j = 0; j < 16; ++j) { g[j] = atomicAdd(&h[j], 0u); ssum += g[j]; }
    part[tid] = ssum;
    __syncthreads();
    for (int off = 1; off < 256; off <<= 1) {     // inclusive suffix scan
        unsigned v = (tid + off < 256) ? part[tid + off] : 0u;
        __syncthreads();
        part[tid] += v;
        __syncthreads();
    }
    unsigned cum = (tid + 1 < 256) ? part[tid + 1] : 0u;  // exclusive suffix
    int loc = -1;
    #pragma unroll
    for (int j = 15; j >= 0; --j) {               // largest in-thread bin first
        cum += g[j];
        if (cum >= PRE_NMS) { loc = tid * 16 + j; break; }
    }
    if (loc >= 0) atomicMax(&best, loc);
    __syncthreads();
    if (tid == 0) tArr[b] = (unsigned)best;       // consumed across kernel boundary
}

// ---------------- K2: compact all elements with bin >= T into candidates ----
__global__ __launch_bounds__(256)
void k_compact(const float* __restrict__ score,
               const unsigned char* __restrict__ mask,
               const unsigned int* __restrict__ tArr,
               unsigned int* __restrict__ cntArr,
               unsigned long long* __restrict__ cand) {
    int chunk = blockIdx.x, b = blockIdx.y, tid = threadIdx.x;
    unsigned T = tArr[b];
    const float4* fg = reinterpret_cast<const float4*>(
        score + (size_t)b * (2 * NA * HWSZ) + (size_t)NA * HWSZ);
    const uchar4* mk = reinterpret_cast<const uchar4*>(mask);
    #pragma unroll
    for (int it = 0; it < 4; ++it) {
        int q = chunk * 1024 + it * 256 + tid;
        if (q >= NANC4) continue;
        float4 v = fg[q];
        uchar4 m = mk[q];
        float av[4] = { m.x ? v.x : -INFINITY, m.y ? v.y : -INFINITY,
                        m.z ? v.z : -INFINITY, m.w ? v.w : -INFINITY };
        #pragma unroll
        for (int c = 0; c < 4; ++c) {
            unsigned ov = f32_ord(av[c]);
            if ((ov >> 20) >= T) {
                int mfull = 4 * q + c;               // memory order a*HWSZ + s
                int a = mfull / HWSZ;
                int s = mfull - a * HWSZ;
                unsigned n = (unsigned)(s * NA + a);  // anchor order (top_k index)
                unsigned slot = atomicAdd(&cntArr[b], 1u);
                if (slot < CAP)
                    cand[(size_t)b * CAP + slot] =
                        ((unsigned long long)ov << 32) |
                        (unsigned long long)(0xFFFFFFFFu - n);  // low idx wins ties
            }
        }
    }
}

// generic in-LDS bitonic sort, descending, S = power of 2 (block-uniform)
__device__ inline void bitonic_desc(unsigned long long* sh, int S, int nthr) {
    for (int k = 2; k <= S; k <<= 1) {
        for (int j = k >> 1; j > 0; j >>= 1) {
            for (int i = threadIdx.x; i < S; i += nthr) {
                int ix = i ^ j;
                if (ix > i) {
                    unsigned long long va = sh[i], vb = sh[ix];
                    bool up = ((i & k) == 0);
                    bool sw = up ? (va < vb) : (va > vb);
                    if (sw) { sh[i] = vb; sh[ix] = va; }
                }
            }
            __syncthreads();
        }
    }
}

// --------- K3: per-batch sort candidates, decode top-100, NMS, write -------
__global__ __launch_bounds__(256)
void k_final(const unsigned long long* __restrict__ cand,
             const unsigned int* __restrict__ cntArr,
             const float* __restrict__ delta,
             const float* __restrict__ img,
             float* __restrict__ out) {
    __shared__ unsigned long long sh[CAP];
    __shared__ float bx1[PRE_NMS], by1[PRE_NMS], bx2[PRE_NMS], by2[PRE_NMS];
    __shared__ float bsc[PRE_NMS], barea[PRE_NMS];
    __shared__ unsigned int supW[PRE_NMS * 4];   // suppress bit-matrix rows
    __shared__ unsigned int keepW[4];
    __shared__ int osrc[PRE_NMS];

    int b = blockIdx.x, tid = threadIdx.x;
    int nc = min((int)cntArr[b], CAP);
    int S = 128;
    while (S < nc) S <<= 1;

    for (int l = tid; l < S; l += 256)
        sh[l] = (l < nc) ? cand[(size_t)b * CAP + l] : 0ull;
    if (tid < 4) keepW[tid] = 0u;
    for (int i = tid; i < PRE_NMS * 4; i += 256) supW[i] = 0u;
    __syncthreads();

    bitonic_desc(sh, S, 256);   // ends with __syncthreads

    float imgH = img[0], imgW = img[1];
    if (tid < PRE_NMS) {
        unsigned long long key = sh[tid];
        float x1 = 0.f, y1 = 0.f, x2 = 0.f, y2 = 0.f, v = -INFINITY, ar = 1.f;
        if (key != 0ull) {   // real candidate (pad keys are exactly 0)
            unsigned n = 0xFFFFFFFFu - (unsigned)(key & 0xFFFFFFFFu);
            v = ord_f32((unsigned)(key >> 32));
            // delta.reshape(B,-1,4): row n = flat elems [4n..4n+3] (contiguous)
            float4 d = reinterpret_cast<const float4*>(
                delta + (size_t)b * (4 * NANC))[n];
            decode_box((int)n, d, imgW, imgH, x1, y1, x2, y2);
            ar = (x2 - x1 + 1.0f) * (y2 - y1 + 1.0f);
        }
        bx1[tid] = x1; by1[tid] = y1; bx2[tid] = x2; by2[tid] = y2;
        bsc[tid] = v;  barea[tid] = ar;
        if (key != 0ull && isfinite(v))
            atomicOr(&keepW[tid >> 5], 1u << (tid & 31));
    }
    __syncthreads();

    // 100x100 suppress matrix: bit j of row i set iff j>i and IoU>thresh
    for (int p = tid; p < PRE_NMS * PRE_NMS; p += 256) {
        int i = p / PRE_NMS;
        int j = p - i * PRE_NMS;
        if (j > i) {
            float ix1 = fmaxf(bx1[i], bx1[j]);
            float iy1 = fmaxf(by1[i], by1[j]);
            float ix2 = fminf(bx2[i], bx2[j]);
            float iy2 = fminf(by2[i], by2[j]);
            float iw = fmaxf(ix2 - ix1 + 1.0f, 0.0f);
            float ih = fmaxf(iy2 - iy1 + 1.0f, 0.0f);
            float inter = iw * ih;
            float iou = inter / (barea[i] + barea[j] - inter);
            if (iou > NMS_THRESH)
                atomicOr(&supW[i * 4 + (j >> 5)], 1u << (j & 31));
        }
    }
    __syncthreads();

    // greedy pass entirely in wave-0 registers (no barriers)
    if (tid < 64) {
        unsigned r0w0 = supW[tid * 4 + 0], r0w1 = supW[tid * 4 + 1];
        unsigned r0w2 = supW[tid * 4 + 2], r0w3 = supW[tid * 4 + 3];
        unsigned r1w0 = 0, r1w1 = 0, r1w2 = 0, r1w3 = 0;
        if (tid < PRE_NMS - 64) {
            r1w0 = supW[(64 + tid) * 4 + 0]; r1w1 = supW[(64 + tid) * 4 + 1];
            r1w2 = supW[(64 + tid) * 4 + 2]; r1w3 = supW[(64 + tid) * 4 + 3];
        }
        unsigned kw0 = keepW[0], kw1 = keepW[1], kw2 = keepW[2], kw3 = keepW[3];
        #pragma unroll
        for (int i = 0; i < PRE_NMS - 1; ++i) {
            unsigned kword = (i < 32) ? kw0 : (i < 64) ? kw1 : (i < 96) ? kw2 : kw3;
            if ((kword >> (i & 31)) & 1u) {   // uniform across the wave
                unsigned s0, s1, s2, s3;
                if (i < 64) {
                    s0 = __shfl(r0w0, i, 64); s1 = __shfl(r0w1, i, 64);
                    s2 = __shfl(r0w2, i, 64); s3 = __shfl(r0w3, i, 64);
                } else {
                    s0 = __shfl(r1w0, i - 64, 64); s1 = __shfl(r1w1, i - 64, 64);
                    s2 = __shfl(r1w2, i - 64, 64); s3 = __shfl(r1w3, i - 64, 64);
                }
                kw0 &= ~s0; kw1 &= ~s1; kw2 &= ~s2; kw3 &= ~s3;
            }
        }
        if (tid == 0) { keepW[0] = kw0; keepW[1] = kw1; keepW[2] = kw2; keepW[3] = kw3; }
    }
    __syncthreads();

    if (tid < PRE_NMS) osrc[tid] = -1;
    __syncthreads();
    if (tid < PRE_NMS) {
        unsigned k0 = keepW[0], k1 = keepW[1], k2 = keepW[2], k3 = keepW[3];
        int w = tid >> 5, bit = tid & 31;
        unsigned kword = (w == 0) ? k0 : (w == 1) ? k1 : (w == 2) ? k2 : k3;
        if ((kword >> bit) & 1u) {
            int pos = __popc(kword & ((1u << bit) - 1u));
            if (w > 0) pos += __popc(k0);
            if (w > 1) pos += __popc(k1);
            if (w > 2) pos += __popc(k2);
            osrc[pos] = tid;
        }
    }
    __syncthreads();

    float* ob = out + (size_t)b * (PRE_NMS * 5);
    if (tid < PRE_NMS) {
        int j = osrc[tid];
        float r0 = 0.f, r1 = 0.f, r2 = 0.f, r3 = 0.f, r4 = 0.f;
        if (j >= 0) { r0 = bx1[j]; r1 = by1[j]; r2 = bx2[j]; r3 = by2[j]; r4 = bsc[j]; }
        ob[tid * 5 + 0] = r0;
        ob[tid * 5 + 1] = r1;
        ob[tid * 5 + 2] = r2;
        ob[tid * 5 + 3] = r3;
        ob[tid * 5 + 4] = r4;
    }
}

// ----------------------------------------------------------------- launch ---
extern "C" void kernel_launch(void* const* d_in, const int* in_sizes, int n_in,
                              void* d_out, int out_size, void* d_ws, size_t ws_size,
                              hipStream_t stream) {
    const float* score = (const float*)d_in[0];
    const float* delta = (const float*)d_in[1];
    const float* img   = (const float*)d_in[2];
    float* out = (float*)d_out;

    int B = in_sizes[0] / (2 * NA * HWSZ);   // 32 for the reference shapes

    // ws layout: [cand: B*CAP u64][ghist: B*NBIN u32][tArr: B][cntArr: B][done: B][mask: NANC u8]
    unsigned long long* cand = (unsigned long long*)d_ws;
    unsigned int* ghist  = (unsigned int*)((char*)d_ws + (size_t)B * CAP * 8);
    unsigned int* tArr   = ghist + (size_t)B * NBIN;
    unsigned int* cntArr = tArr + B;
    unsigned int* done   = cntArr + B;
    unsigned char* mask  = (unsigned char*)(done + B);

    // zero ghist + tArr + cntArr + done in one strided sweep (contiguous u32;
    // tArr is overwritten by k_hist before any read, so zeroing it is harmless)
    int nzero = B * NBIN + 3 * B;
    k_mask<<<(NANC + 255) / 256, 256, 0, stream>>>(delta, img, mask, ghist, nzero);
    dim3 gh(NCH, B);
    k_hist<<<gh, 256, 0, stream>>>(score, mask, ghist, done, tArr);
    k_compact<<<gh, 256, 0, stream>>>(score, mask, tArr, cntArr, cand);
    k_final<<<B, 256, 0, stream>>>(cand, cntArr, delta, img, out);
}

// Round 9
// 161.177 us; speedup vs baseline: 1.1286x; 1.1286x over previous
//
#include <hip/hip_runtime.h>
#include <math.h>

// Problem constants (reference setup_inputs: B=32, H=80, W=120, A=9)
#define NA     9
#define HH     80
#define WWID   120
#define HWSZ   (HH * WWID)        // 9600
#define NANC   (HWSZ * NA)        // 86400 anchors per image
#define NANC4  (NANC / 4)         // 21600 float4 groups
#define PRE_NMS 100
#define NMS_THRESH 0.3f
#define MIN_SIZE 8.0f
#define STRIDE_F 16.0f
#define NBIN   4096               // 12-bit histogram of ordered-f32
#define CAP    2048               // per-batch candidate cap (expected ~183)
#define NCH    22                 // chunks of 1024 float4-groups (22*1024 >= 21600)

// Anchor geometry: all 9 anchors share center (8,8); widths/heights exact
// (verified against _generate_anchors(16,(0.5,1,2),(8,16,32))).
__constant__ float c_aw[NA] = {184.f, 368.f, 736.f, 128.f, 256.f, 512.f,  88.f, 176.f, 352.f};
__constant__ float c_ah[NA] = { 96.f, 192.f, 384.f, 128.f, 256.f, 512.f, 176.f, 352.f, 704.f};

// ---------------------------------------------------------------- decode ----
__device__ inline void decode_box(int n, float4 d, float imgW, float imgH,
                                  float& x1, float& y1, float& x2, float& y2) {
    int a = n % NA;
    int s = n / NA;
    int yy = s / WWID;
    int xx = s - yy * WWID;
    float aw = c_aw[a], ah = c_ah[a];
    float acx = 8.0f + STRIDE_F * (float)xx;
    float acy = 8.0f + STRIDE_F * (float)yy;
    float pcx = d.x * aw + acx;
    float pcy = d.y * ah + acy;
    float pw  = expf(d.z) * aw;
    float ph  = expf(d.w) * ah;
    x1 = pcx - 0.5f * pw;
    y1 = pcy - 0.5f * ph;
    x2 = pcx + 0.5f * pw;
    y2 = pcy + 0.5f * ph;
    float mx = imgW - 1.0f, my = imgH - 1.0f;
    x1 = fminf(fmaxf(x1, 0.0f), mx);
    x2 = fminf(fmaxf(x2, 0.0f), mx);
    y1 = fminf(fmaxf(y1, 0.0f), my);
    y2 = fminf(fmaxf(y2, 0.0f), my);
}

// order-preserving uint mapping (monotonic for all floats incl +-inf)
__device__ inline unsigned int f32_ord(float v) {
    unsigned int u = __float_as_uint(v);
    return (u & 0x80000000u) ? ~u : (u | 0x80000000u);
}
__device__ inline float ord_f32(unsigned int ov) {
    unsigned int u = (ov & 0x80000000u) ? (ov ^ 0x80000000u) : ~ov;
    return __uint_as_float(u);
}

// ---------------- K0: batch-0 size mask + zero cntArr -----------------------
// mask stored in score-memory order m = a*HWSZ + s so later reads coalesce.
__global__ void k_mask(const float* __restrict__ delta,
                       const float* __restrict__ img,
                       unsigned char* __restrict__ mask,
                       unsigned int* __restrict__ zero_base, int nzero) {
    int gid = blockIdx.x * blockDim.x + threadIdx.x;
    for (int i = gid; i < nzero; i += gridDim.x * blockDim.x) zero_base[i] = 0u;
    if (gid >= NANC) return;
    float4 d = reinterpret_cast<const float4*>(delta)[gid];  // batch 0, contiguous
    float imgH = img[0], imgW = img[1];
    float x1, y1, x2, y2;
    decode_box(gid, d, imgW, imgH, x1, y1, x2, y2);
    float ws = x2 - x1 + 1.0f;
    float hs = y2 - y1 + 1.0f;
    int a = gid % NA;
    int s = gid / NA;
    mask[a * HWSZ + s] = (ws >= MIN_SIZE && hs >= MIN_SIZE) ? 1 : 0;
}

// ------ K1: per-(chunk,batch) LDS histogram -> PRIVATE global slice ---------
// No global atomics, no cross-block coupling: block (chunk,b) owns slice
// ghist_part[b][chunk][0..NBIN). Plain coalesced stores; slices summed by
// k_thresh. (Decisive experiment vs r8's 45us global-atomic-merge k_hist.)
__global__ __launch_bounds__(256)
void k_hist(const float* __restrict__ score,
            const unsigned char* __restrict__ mask,
            unsigned int* __restrict__ ghist_part) {
    __shared__ unsigned int lh[NBIN];
    int chunk = blockIdx.x, b = blockIdx.y, tid = threadIdx.x;
    for (int i = tid; i < NBIN; i += 256) lh[i] = 0u;
    __syncthreads();

    const float4* fg = reinterpret_cast<const float4*>(
        score + (size_t)b * (2 * NA * HWSZ) + (size_t)NA * HWSZ);
    const uchar4* mk = reinterpret_cast<const uchar4*>(mask);
    #pragma unroll
    for (int it = 0; it < 4; ++it) {
        int q = chunk * 1024 + it * 256 + tid;
        if (q < NANC4) {
            float4 v = fg[q];
            uchar4 m = mk[q];
            float a0 = m.x ? v.x : -INFINITY;
            float a1 = m.y ? v.y : -INFINITY;
            float a2 = m.z ? v.z : -INFINITY;
            float a3 = m.w ? v.w : -INFINITY;
            atomicAdd(&lh[f32_ord(a0) >> 20], 1u);
            atomicAdd(&lh[f32_ord(a1) >> 20], 1u);
            atomicAdd(&lh[f32_ord(a2) >> 20], 1u);
            atomicAdd(&lh[f32_ord(a3) >> 20], 1u);
        }
    }
    __syncthreads();
    unsigned int* gp = ghist_part + ((size_t)b * NCH + chunk) * NBIN;
    for (int i = tid; i < NBIN; i += 256)
        gp[i] = lh[i];                 // plain coalesced store, no atomics
}

// ------ K2: per-batch sum of NCH private slices -> suffix-scan -> T ---------
// T = max bin with count(bins >= T) >= 100  => global top-100 all in bins >= T.
__global__ __launch_bounds__(256)
void k_thresh(const unsigned int* __restrict__ ghist_part,
              unsigned int* __restrict__ tArr) {
    __shared__ unsigned int part[256];
    __shared__ int best;
    int b = blockIdx.x, tid = threadIdx.x;
    if (tid == 0) best = 0;

    // thread t owns bins [t*16, t*16+16); sum over NCH slices with uint4 loads
    unsigned g[16];
    #pragma unroll
    for (int j = 0; j < 16; ++j) g[j] = 0u;
    const uint4* base = reinterpret_cast<const uint4*>(
        ghist_part + (size_t)b * NCH * NBIN);
    for (int c = 0; c < NCH; ++c) {
        const uint4* p = base + c * (NBIN / 4) + tid * 4;
        #pragma unroll
        for (int k = 0; k < 4; ++k) {
            uint4 v = p[k];
            g[4 * k + 0] += v.x;
            g[4 * k + 1] += v.y;
            g[4 * k + 2] += v.z;
            g[4 * k + 3] += v.w;
        }
    }
    unsigned ssum = 0;
    #pragma unroll
    for (int j = 0; j < 16; ++j) ssum += g[j];
    part[tid] = ssum;
    __syncthreads();
    for (int off = 1; off < 256; off <<= 1) {     // inclusive suffix scan
        unsigned v = (tid + off < 256) ? part[tid + off] : 0u;
        __syncthreads();
        part[tid] += v;
        __syncthreads();
    }
    unsigned cum = (tid + 1 < 256) ? part[tid + 1] : 0u;  // exclusive suffix
    int loc = -1;
    #pragma unroll
    for (int j = 15; j >= 0; --j) {               // largest in-thread bin first
        cum += g[j];
        if (cum >= PRE_NMS) { loc = tid * 16 + j; break; }
    }
    if (loc >= 0) atomicMax(&best, loc);
    __syncthreads();
    if (tid == 0) tArr[b] = (unsigned)best;
}

// ---------------- K3: compact all elements with bin >= T into candidates ----
__global__ __launch_bounds__(256)
void k_compact(const float* __restrict__ score,
               const unsigned char* __restrict__ mask,
               const unsigned int* __restrict__ tArr,
               unsigned int* __restrict__ cntArr,
               unsigned long long* __restrict__ cand) {
    int chunk = blockIdx.x, b = blockIdx.y, tid = threadIdx.x;
    unsigned T = tArr[b];
    const float4* fg = reinterpret_cast<const float4*>(
        score + (size_t)b * (2 * NA * HWSZ) + (size_t)NA * HWSZ);
    const uchar4* mk = reinterpret_cast<const uchar4*>(mask);
    #pragma unroll
    for (int it = 0; it < 4; ++it) {
        int q = chunk * 1024 + it * 256 + tid;
        if (q >= NANC4) continue;
        float4 v = fg[q];
        uchar4 m = mk[q];
        float av[4] = { m.x ? v.x : -INFINITY, m.y ? v.y : -INFINITY,
                        m.z ? v.z : -INFINITY, m.w ? v.w : -INFINITY };
        #pragma unroll
        for (int c = 0; c < 4; ++c) {
            unsigned ov = f32_ord(av[c]);
            if ((ov >> 20) >= T) {
                int mfull = 4 * q + c;               // memory order a*HWSZ + s
                int a = mfull / HWSZ;
                int s = mfull - a * HWSZ;
                unsigned n = (unsigned)(s * NA + a);  // anchor order (top_k index)
                unsigned slot = atomicAdd(&cntArr[b], 1u);
                if (slot < CAP)
                    cand[(size_t)b * CAP + slot] =
                        ((unsigned long long)ov << 32) |
                        (unsigned long long)(0xFFFFFFFFu - n);  // low idx wins ties
            }
        }
    }
}

// generic in-LDS bitonic sort, descending, S = power of 2 (block-uniform)
__device__ inline void bitonic_desc(unsigned long long* sh, int S, int nthr) {
    for (int k = 2; k <= S; k <<= 1) {
        for (int j = k >> 1; j > 0; j >>= 1) {
            for (int i = threadIdx.x; i < S; i += nthr) {
                int ix = i ^ j;
                if (ix > i) {
                    unsigned long long va = sh[i], vb = sh[ix];
                    bool up = ((i & k) == 0);
                    bool sw = up ? (va < vb) : (va > vb);
                    if (sw) { sh[i] = vb; sh[ix] = va; }
                }
            }
            __syncthreads();
        }
    }
}

// --------- K4: per-batch sort candidates, decode top-100, NMS, write -------
__global__ __launch_bounds__(256)
void k_final(const unsigned long long* __restrict__ cand,
             const unsigned int* __restrict__ cntArr,
             const float* __restrict__ delta,
             const float* __restrict__ img,
             float* __restrict__ out) {
    __shared__ unsigned long long sh[CAP];
    __shared__ float bx1[PRE_NMS], by1[PRE_NMS], bx2[PRE_NMS], by2[PRE_NMS];
    __shared__ float bsc[PRE_NMS], barea[PRE_NMS];
    __shared__ unsigned int supW[PRE_NMS * 4];   // suppress bit-matrix rows
    __shared__ unsigned int keepW[4];
    __shared__ int osrc[PRE_NMS];

    int b = blockIdx.x, tid = threadIdx.x;
    int nc = min((int)cntArr[b], CAP);
    int S = 128;
    while (S < nc) S <<= 1;

    for (int l = tid; l < S; l += 256)
        sh[l] = (l < nc) ? cand[(size_t)b * CAP + l] : 0ull;
    if (tid < 4) keepW[tid] = 0u;
    for (int i = tid; i < PRE_NMS * 4; i += 256) supW[i] = 0u;
    __syncthreads();

    bitonic_desc(sh, S, 256);   // ends with __syncthreads

    float imgH = img[0], imgW = img[1];
    if (tid < PRE_NMS) {
        unsigned long long key = sh[tid];
        float x1 = 0.f, y1 = 0.f, x2 = 0.f, y2 = 0.f, v = -INFINITY, ar = 1.f;
        if (key != 0ull) {   // real candidate (pad keys are exactly 0)
            unsigned n = 0xFFFFFFFFu - (unsigned)(key & 0xFFFFFFFFu);
            v = ord_f32((unsigned)(key >> 32));
            // delta.reshape(B,-1,4): row n = flat elems [4n..4n+3] (contiguous)
            float4 d = reinterpret_cast<const float4*>(
                delta + (size_t)b * (4 * NANC))[n];
            decode_box((int)n, d, imgW, imgH, x1, y1, x2, y2);
            ar = (x2 - x1 + 1.0f) * (y2 - y1 + 1.0f);
        }
        bx1[tid] = x1; by1[tid] = y1; bx2[tid] = x2; by2[tid] = y2;
        bsc[tid] = v;  barea[tid] = ar;
        if (key != 0ull && isfinite(v))
            atomicOr(&keepW[tid >> 5], 1u << (tid & 31));
    }
    __syncthreads();

    // 100x100 suppress matrix: bit j of row i set iff j>i and IoU>thresh
    for (int p = tid; p < PRE_NMS * PRE_NMS; p += 256) {
        int i = p / PRE_NMS;
        int j = p - i * PRE_NMS;
        if (j > i) {
            float ix1 = fmaxf(bx1[i], bx1[j]);
            float iy1 = fmaxf(by1[i], by1[j]);
            float ix2 = fminf(bx2[i], bx2[j]);
            float iy2 = fminf(by2[i], by2[j]);
            float iw = fmaxf(ix2 - ix1 + 1.0f, 0.0f);
            float ih = fmaxf(iy2 - iy1 + 1.0f, 0.0f);
            float inter = iw * ih;
            float iou = inter / (barea[i] + barea[j] - inter);
            if (iou > NMS_THRESH)
                atomicOr(&supW[i * 4 + (j >> 5)], 1u << (j & 31));
        }
    }
    __syncthreads();

    // greedy pass entirely in wave-0 registers (no barriers)
    if (tid < 64) {
        unsigned r0w0 = supW[tid * 4 + 0], r0w1 = supW[tid * 4 + 1];
        unsigned r0w2 = supW[tid * 4 + 2], r0w3 = supW[tid * 4 + 3];
        unsigned r1w0 = 0, r1w1 = 0, r1w2 = 0, r1w3 = 0;
        if (tid < PRE_NMS - 64) {
            r1w0 = supW[(64 + tid) * 4 + 0]; r1w1 = supW[(64 + tid) * 4 + 1];
            r1w2 = supW[(64 + tid) * 4 + 2]; r1w3 = supW[(64 + tid) * 4 + 3];
        }
        unsigned kw0 = keepW[0], kw1 = keepW[1], kw2 = keepW[2], kw3 = keepW[3];
        #pragma unroll
        for (int i = 0; i < PRE_NMS - 1; ++i) {
            unsigned kword = (i < 32) ? kw0 : (i < 64) ? kw1 : (i < 96) ? kw2 : kw3;
            if ((kword >> (i & 31)) & 1u) {   // uniform across the wave
                unsigned s0, s1, s2, s3;
                if (i < 64) {
                    s0 = __shfl(r0w0, i, 64); s1 = __shfl(r0w1, i, 64);
                    s2 = __shfl(r0w2, i, 64); s3 = __shfl(r0w3, i, 64);
                } else {
                    s0 = __shfl(r1w0, i - 64, 64); s1 = __shfl(r1w1, i - 64, 64);
                    s2 = __shfl(r1w2, i - 64, 64); s3 = __shfl(r1w3, i - 64, 64);
                }
                kw0 &= ~s0; kw1 &= ~s1; kw2 &= ~s2; kw3 &= ~s3;
            }
        }
        if (tid == 0) { keepW[0] = kw0; keepW[1] = kw1; keepW[2] = kw2; keepW[3] = kw3; }
    }
    __syncthreads();

    if (tid < PRE_NMS) osrc[tid] = -1;
    __syncthreads();
    if (tid < PRE_NMS) {
        unsigned k0 = keepW[0], k1 = keepW[1], k2 = keepW[2], k3 = keepW[3];
        int w = tid >> 5, bit = tid & 31;
        unsigned kword = (w == 0) ? k0 : (w == 1) ? k1 : (w == 2) ? k2 : k3;
        if ((kword >> bit) & 1u) {
            int pos = __popc(kword & ((1u << bit) - 1u));
            if (w > 0) pos += __popc(k0);
            if (w > 1) pos += __popc(k1);
            if (w > 2) pos += __popc(k2);
            osrc[pos] = tid;
        }
    }
    __syncthreads();

    float* ob = out + (size_t)b * (PRE_NMS * 5);
    if (tid < PRE_NMS) {
        int j = osrc[tid];
        float r0 = 0.f, r1 = 0.f, r2 = 0.f, r3 = 0.f, r4 = 0.f;
        if (j >= 0) { r0 = bx1[j]; r1 = by1[j]; r2 = bx2[j]; r3 = by2[j]; r4 = bsc[j]; }
        ob[tid * 5 + 0] = r0;
        ob[tid * 5 + 1] = r1;
        ob[tid * 5 + 2] = r2;
        ob[tid * 5 + 3] = r3;
        ob[tid * 5 + 4] = r4;
    }
}

// ----------------------------------------------------------------- launch ---
extern "C" void kernel_launch(void* const* d_in, const int* in_sizes, int n_in,
                              void* d_out, int out_size, void* d_ws, size_t ws_size,
                              hipStream_t stream) {
    const float* score = (const float*)d_in[0];
    const float* delta = (const float*)d_in[1];
    const float* img   = (const float*)d_in[2];
    float* out = (float*)d_out;

    int B = in_sizes[0] / (2 * NA * HWSZ);   // 32 for the reference shapes

    // ws layout:
    // [cand: B*CAP u64][ghist_part: B*NCH*NBIN u32][tArr: B][cntArr: B][mask: NANC u8]
    unsigned long long* cand = (unsigned long long*)d_ws;
    unsigned int* ghist_part = (unsigned int*)((char*)d_ws + (size_t)B * CAP * 8);
    unsigned int* tArr   = ghist_part + (size_t)B * NCH * NBIN;
    unsigned int* cntArr = tArr + B;
    unsigned char* mask  = (unsigned char*)(cntArr + B);

    // only cntArr needs zeroing (ghist_part slices are fully overwritten,
    // tArr is written unconditionally by k_thresh before any read)
    k_mask<<<(NANC + 255) / 256, 256, 0, stream>>>(delta, img, mask, cntArr, B);
    dim3 gh(NCH, B);
    k_hist<<<gh, 256, 0, stream>>>(score, mask, ghist_part);
    k_thresh<<<B, 256, 0, stream>>>(ghist_part, tArr);
    k_compact<<<gh, 256, 0, stream>>>(score, mask, tArr, cntArr, cand);
    k_final<<<B, 256, 0, stream>>>(cand, cntArr, delta, img, out);
}

// Round 14
// 141.833 us; speedup vs baseline: 1.2825x; 1.1364x over previous
//
#include <hip/hip_runtime.h>
#include <math.h>

// Problem constants (reference setup_inputs: B=32, H=80, W=120, A=9)
#define NA     9
#define HH     80
#define WWID   120
#define HWSZ   (HH * WWID)        // 9600
#define NANC   (HWSZ * NA)        // 86400 anchors per image
#define NANC4  (NANC / 4)         // 21600 float4 groups
#define PRE_NMS 100
#define NMS_THRESH 0.3f
#define MIN_SIZE 8.0f
#define STRIDE_F 16.0f
#define NCH    22                 // chunks of 1024 float4-groups (22*1024 >= 21600)
#define SLOTS  46                 // per-(batch,chunk) candidate slots
#define NFAST  (NCH * SLOTS)      // 1012 <= 1024 (fast-path sort size)
#define NBIN   4096               // fallback histogram bins
#define CAPF   2048               // fallback candidate cap (matches prior rounds)
// Fast-path threshold: scores >= 2.75f. ord(2.75f)=0x40300000|0x80000000.
// N(0,1): p=0.00298 -> ~257 cand/batch (need>=100, 10 sigma), ~11.7/chunk
// (SLOTS=46 is 10 sigma). Both conditions VERIFIED at runtime in k_final;
// exact in-block fallback if violated, so correctness never depends on this.
#define T0ORD  0xC0300000u

// Anchor geometry: all 9 anchors share center (8,8); widths/heights exact
// (verified against _generate_anchors(16,(0.5,1,2),(8,16,32))).
__constant__ float c_aw[NA] = {184.f, 368.f, 736.f, 128.f, 256.f, 512.f,  88.f, 176.f, 352.f};
__constant__ float c_ah[NA] = { 96.f, 192.f, 384.f, 128.f, 256.f, 512.f, 176.f, 352.f, 704.f};

// ---------------------------------------------------------------- decode ----
__device__ inline void decode_box(int n, float4 d, float imgW, float imgH,
                                  float& x1, float& y1, float& x2, float& y2) {
    int a = n % NA;
    int s = n / NA;
    int yy = s / WWID;
    int xx = s - yy * WWID;
    float aw = c_aw[a], ah = c_ah[a];
    float acx = 8.0f + STRIDE_F * (float)xx;
    float acy = 8.0f + STRIDE_F * (float)yy;
    float pcx = d.x * aw + acx;
    float pcy = d.y * ah + acy;
    float pw  = expf(d.z) * aw;
    float ph  = expf(d.w) * ah;
    x1 = pcx - 0.5f * pw;
    y1 = pcy - 0.5f * ph;
    x2 = pcx + 0.5f * pw;
    y2 = pcy + 0.5f * ph;
    float mx = imgW - 1.0f, my = imgH - 1.0f;
    x1 = fminf(fmaxf(x1, 0.0f), mx);
    x2 = fminf(fmaxf(x2, 0.0f), mx);
    y1 = fminf(fmaxf(y1, 0.0f), my);
    y2 = fminf(fmaxf(y2, 0.0f), my);
}

// order-preserving uint mapping (monotonic for all floats incl +-inf)
__device__ inline unsigned int f32_ord(float v) {
    unsigned int u = __float_as_uint(v);
    return (u & 0x80000000u) ? ~u : (u | 0x80000000u);
}
__device__ inline float ord_f32(unsigned int ov) {
    unsigned int u = (ov & 0x80000000u) ? (ov ^ 0x80000000u) : ~ov;
    return __uint_as_float(u);
}

// batch-0 min-size mask, recomputed inline (delta0 is 1.4MB -> L2-resident)
__device__ inline bool keep_mask(int n, const float4* __restrict__ d0,
                                 float imgW, float imgH) {
    float x1, y1, x2, y2;
    decode_box(n, d0[n], imgW, imgH, x1, y1, x2, y2);
    return (x2 - x1 + 1.0f >= MIN_SIZE) && (y2 - y1 + 1.0f >= MIN_SIZE);
}

// ---- K1: static-threshold compact into per-block private slot regions -----
// No global atomics, no zeroing dependency: block (chunk,b) owns
// cand[(b*NCH+chunk)*SLOTS ..+SLOTS) and writes ALL of it (hits + 0-pad),
// plus its true hit count (overflow detectable by k_final).
__global__ __launch_bounds__(256)
void k_compact(const float* __restrict__ score,
               const float* __restrict__ delta,
               const float* __restrict__ img,
               unsigned long long* __restrict__ cand,
               unsigned int* __restrict__ cnts) {
    __shared__ unsigned int lcnt;
    int chunk = blockIdx.x, b = blockIdx.y, tid = threadIdx.x;
    if (tid == 0) lcnt = 0u;
    __syncthreads();

    const float4* fg = reinterpret_cast<const float4*>(
        score + (size_t)b * (2 * NA * HWSZ) + (size_t)NA * HWSZ);
    const float4* d0 = reinterpret_cast<const float4*>(delta);  // batch 0
    float imgH = img[0], imgW = img[1];
    unsigned long long* myc = cand + ((size_t)b * NCH + chunk) * SLOTS;

    #pragma unroll
    for (int it = 0; it < 4; ++it) {
        int q = chunk * 1024 + it * 256 + tid;
        if (q < NANC4) {
            float4 v = fg[q];
            float vv[4] = {v.x, v.y, v.z, v.w};
            #pragma unroll
            for (int c = 0; c < 4; ++c) {
                unsigned ov = f32_ord(vv[c]);
                if (ov >= T0ORD) {                    // ~0.3% of elements
                    int m = 4 * q + c;                // score order a*HWSZ+s
                    int a = m / HWSZ;
                    int s = m - a * HWSZ;
                    int n = s * NA + a;               // anchor order (top_k idx)
                    if (keep_mask(n, d0, imgW, imgH)) {
                        unsigned slot = atomicAdd(&lcnt, 1u);
                        if (slot < SLOTS)
                            myc[slot] = ((unsigned long long)ov << 32) |
                                        (unsigned long long)(0xFFFFFFFFu - (unsigned)n);
                    }
                }
            }
        }
    }
    __syncthreads();
    unsigned cnt = lcnt;
    if (tid == 0) cnts[b * NCH + chunk] = cnt;        // true count (may exceed SLOTS)
    for (unsigned l = cnt + tid; l < SLOTS; l += 256) myc[l] = 0ull;  // zero-pad
}

// generic in-LDS bitonic sort, descending, S = power of 2 (block-uniform)
__device__ inline void bitonic_desc(unsigned long long* sh, int S, int nthr) {
    for (int k = 2; k <= S; k <<= 1) {
        for (int j = k >> 1; j > 0; j >>= 1) {
            for (int i = threadIdx.x; i < S; i += nthr) {
                int ix = i ^ j;
                if (ix > i) {
                    unsigned long long va = sh[i], vb = sh[ix];
                    bool up = ((i & k) == 0);
                    bool sw = up ? (va < vb) : (va > vb);
                    if (sw) { sh[i] = vb; sh[ix] = va; }
                }
            }
            __syncthreads();
        }
    }
}

// ---- K2: verify fast-path conditions, sort, decode top-100, NMS, write ----
__global__ __launch_bounds__(256)
void k_final(const unsigned long long* __restrict__ cand,
             const unsigned int* __restrict__ cnts,
             const float* __restrict__ score,
             const float* __restrict__ delta,
             const float* __restrict__ img,
             float* __restrict__ out) {
    __shared__ unsigned long long sh[CAPF];          // 16KB; aliased in fallback
    __shared__ float bx1[PRE_NMS], by1[PRE_NMS], bx2[PRE_NMS], by2[PRE_NMS];
    __shared__ float bsc[PRE_NMS], barea[PRE_NMS];
    __shared__ unsigned int supW[PRE_NMS * 4];
    __shared__ unsigned int keepW[4];
    __shared__ int osrc[PRE_NMS];
    __shared__ unsigned int part[256];
    __shared__ int best;
    __shared__ unsigned int scnt;

    int b = blockIdx.x, tid = threadIdx.x;
    float imgH = img[0], imgW = img[1];
    const float4* fg = reinterpret_cast<const float4*>(
        score + (size_t)b * (2 * NA * HWSZ) + (size_t)NA * HWSZ);
    const float4* d0 = reinterpret_cast<const float4*>(delta);  // batch 0 (mask)

    // fast-path validity: every chunk fit its slots AND total >= 100
    // (uniform loads -> 'fast' is block-uniform; branches barrier-safe)
    unsigned total = 0; bool over = false;
    for (int c = 0; c < NCH; ++c) {
        unsigned cc = cnts[b * NCH + c];
        total += cc;
        over = over || (cc > SLOTS);
    }
    bool fast = (!over) && (total >= PRE_NMS);

    int S;
    if (fast) {
        // top-100 all have v >= T0 (since |{v>=T0}| = total >= 100), and the
        // slot regions contain exactly {v >= T0, unmasked} -> superset. exact.
        const unsigned long long* src = cand + (size_t)b * NFAST;
        for (int l = tid; l < 1024; l += 256)
            sh[l] = (l < NFAST) ? src[l] : 0ull;
        S = 1024;
    } else {
        // exact fallback (never taken for the benchmark input): in-block
        // 4096-bin histogram -> threshold bin T -> recollect (validated math)
        unsigned int* lh = reinterpret_cast<unsigned int*>(sh);  // 4096 bins
        for (int i = tid; i < NBIN; i += 256) lh[i] = 0u;
        if (tid == 0) best = 0;
        __syncthreads();
        for (int q = tid; q < NANC4; q += 256) {
            float4 v = fg[q];
            float vv[4] = {v.x, v.y, v.z, v.w};
            #pragma unroll
            for (int c = 0; c < 4; ++c) {
                int m = 4 * q + c;
                int a = m / HWSZ;
                int s = m - a * HWSZ;
                int n = s * NA + a;
                float av = keep_mask(n, d0, imgW, imgH) ? vv[c] : -INFINITY;
                atomicAdd(&lh[f32_ord(av) >> 20], 1u);
            }
        }
        __syncthreads();
        unsigned g[16]; unsigned ssum = 0;
        #pragma unroll
        for (int j = 0; j < 16; ++j) { g[j] = lh[tid * 16 + j]; ssum += g[j]; }
        part[tid] = ssum;
        __syncthreads();
        for (int off = 1; off < 256; off <<= 1) {
            unsigned v = (tid + off < 256) ? part[tid + off] : 0u;
            __syncthreads();
            part[tid] += v;
            __syncthreads();
        }
        unsigned cum = (tid + 1 < 256) ? part[tid + 1] : 0u;
        int loc = -1;
        #pragma unroll
        for (int j = 15; j >= 0; --j) {
            cum += g[j];
            if (cum >= PRE_NMS) { loc = tid * 16 + j; break; }
        }
        if (loc >= 0) atomicMax(&best, loc);
        __syncthreads();
        unsigned T = (unsigned)best;
        if (tid == 0) scnt = 0u;
        for (int l = tid; l < CAPF; l += 256) sh[l] = 0ull;  // overwrites lh
        __syncthreads();
        for (int q = tid; q < NANC4; q += 256) {
            float4 v = fg[q];
            float vv[4] = {v.x, v.y, v.z, v.w};
            #pragma unroll
            for (int c = 0; c < 4; ++c) {
                int m = 4 * q + c;
                int a = m / HWSZ;
                int s = m - a * HWSZ;
                int n = s * NA + a;
                float av = keep_mask(n, d0, imgW, imgH) ? vv[c] : -INFINITY;
                unsigned ov = f32_ord(av);
                if ((ov >> 20) >= T) {
                    unsigned slot = atomicAdd(&scnt, 1u);
                    if (slot < CAPF)
                        sh[slot] = ((unsigned long long)ov << 32) |
                                   (unsigned long long)(0xFFFFFFFFu - (unsigned)n);
                }
            }
        }
        S = CAPF;
    }
    if (tid < 4) keepW[tid] = 0u;
    for (int i = tid; i < PRE_NMS * 4; i += 256) supW[i] = 0u;
    __syncthreads();

    bitonic_desc(sh, S, 256);   // ends with __syncthreads

    // ---------------- validated tail (unchanged from round 9) --------------
    if (tid < PRE_NMS) {
        unsigned long long key = sh[tid];
        float x1 = 0.f, y1 = 0.f, x2 = 0.f, y2 = 0.f, v = -INFINITY, ar = 1.f;
        if (key != 0ull) {   // real candidate (pad keys are exactly 0)
            unsigned n = 0xFFFFFFFFu - (unsigned)(key & 0xFFFFFFFFu);
            v = ord_f32((unsigned)(key >> 32));
            float4 d = reinterpret_cast<const float4*>(
                delta + (size_t)b * (4 * NANC))[n];
            decode_box((int)n, d, imgW, imgH, x1, y1, x2, y2);
            ar = (x2 - x1 + 1.0f) * (y2 - y1 + 1.0f);
        }
        bx1[tid] = x1; by1[tid] = y1; bx2[tid] = x2; by2[tid] = y2;
        bsc[tid] = v;  barea[tid] = ar;
        if (key != 0ull && isfinite(v))
            atomicOr(&keepW[tid >> 5], 1u << (tid & 31));
    }
    __syncthreads();

    for (int p = tid; p < PRE_NMS * PRE_NMS; p += 256) {
        int i = p / PRE_NMS;
        int j = p - i * PRE_NMS;
        if (j > i) {
            float ix1 = fmaxf(bx1[i], bx1[j]);
            float iy1 = fmaxf(by1[i], by1[j]);
            float ix2 = fminf(bx2[i], bx2[j]);
            float iy2 = fminf(by2[i], by2[j]);
            float iw = fmaxf(ix2 - ix1 + 1.0f, 0.0f);
            float ih = fmaxf(iy2 - iy1 + 1.0f, 0.0f);
            float inter = iw * ih;
            float iou = inter / (barea[i] + barea[j] - inter);
            if (iou > NMS_THRESH)
                atomicOr(&supW[i * 4 + (j >> 5)], 1u << (j & 31));
        }
    }
    __syncthreads();

    if (tid < 64) {
        unsigned r0w0 = supW[tid * 4 + 0], r0w1 = supW[tid * 4 + 1];
        unsigned r0w2 = supW[tid * 4 + 2], r0w3 = supW[tid * 4 + 3];
        unsigned r1w0 = 0, r1w1 = 0, r1w2 = 0, r1w3 = 0;
        if (tid < PRE_NMS - 64) {
            r1w0 = supW[(64 + tid) * 4 + 0]; r1w1 = supW[(64 + tid) * 4 + 1];
            r1w2 = supW[(64 + tid) * 4 + 2]; r1w3 = supW[(64 + tid) * 4 + 3];
        }
        unsigned kw0 = keepW[0], kw1 = keepW[1], kw2 = keepW[2], kw3 = keepW[3];
        #pragma unroll
        for (int i = 0; i < PRE_NMS - 1; ++i) {
            unsigned kword = (i < 32) ? kw0 : (i < 64) ? kw1 : (i < 96) ? kw2 : kw3;
            if ((kword >> (i & 31)) & 1u) {
                unsigned s0, s1, s2, s3;
                if (i < 64) {
                    s0 = __shfl(r0w0, i, 64); s1 = __shfl(r0w1, i, 64);
                    s2 = __shfl(r0w2, i, 64); s3 = __shfl(r0w3, i, 64);
                } else {
                    s0 = __shfl(r1w0, i - 64, 64); s1 = __shfl(r1w1, i - 64, 64);
                    s2 = __shfl(r1w2, i - 64, 64); s3 = __shfl(r1w3, i - 64, 64);
                }
                kw0 &= ~s0; kw1 &= ~s1; kw2 &= ~s2; kw3 &= ~s3;
            }
        }
        if (tid == 0) { keepW[0] = kw0; keepW[1] = kw1; keepW[2] = kw2; keepW[3] = kw3; }
    }
    __syncthreads();

    if (tid < PRE_NMS) osrc[tid] = -1;
    __syncthreads();
    if (tid < PRE_NMS) {
        unsigned k0 = keepW[0], k1 = keepW[1], k2 = keepW[2], k3 = keepW[3];
        int w = tid >> 5, bit = tid & 31;
        unsigned kword = (w == 0) ? k0 : (w == 1) ? k1 : (w == 2) ? k2 : k3;
        if ((kword >> bit) & 1u) {
            int pos = __popc(kword & ((1u << bit) - 1u));
            if (w > 0) pos += __popc(k0);
            if (w > 1) pos += __popc(k1);
            if (w > 2) pos += __popc(k2);
            osrc[pos] = tid;
        }
    }
    __syncthreads();

    float* ob = out + (size_t)b * (PRE_NMS * 5);
    if (tid < PRE_NMS) {
        int j = osrc[tid];
        float r0 = 0.f, r1 = 0.f, r2 = 0.f, r3 = 0.f, r4 = 0.f;
        if (j >= 0) { r0 = bx1[j]; r1 = by1[j]; r2 = bx2[j]; r3 = by2[j]; r4 = bsc[j]; }
        ob[tid * 5 + 0] = r0;
        ob[tid * 5 + 1] = r1;
        ob[tid * 5 + 2] = r2;
        ob[tid * 5 + 3] = r3;
        ob[tid * 5 + 4] = r4;
    }
}

// ----------------------------------------------------------------- launch ---
extern "C" void kernel_launch(void* const* d_in, const int* in_sizes, int n_in,
                              void* d_out, int out_size, void* d_ws, size_t ws_size,
                              hipStream_t stream) {
    const float* score = (const float*)d_in[0];
    const float* delta = (const float*)d_in[1];
    const float* img   = (const float*)d_in[2];
    float* out = (float*)d_out;

    int B = in_sizes[0] / (2 * NA * HWSZ);   // 32 for the reference shapes

    // ws layout: [cand: B*NCH*SLOTS u64][cnts: B*NCH u32]  (~262KB total)
    // Every consumed word is written this call (slots zero-padded, cnts
    // unconditional) -> no zeroing kernel, safe under 0xAA re-poison.
    unsigned long long* cand = (unsigned long long*)d_ws;
    unsigned int* cnts = (unsigned int*)((char*)d_ws +
                          (size_t)B * NCH * SLOTS * sizeof(unsigned long long));

    dim3 g1(NCH, B);
    k_compact<<<g1, 256, 0, stream>>>(score, delta, img, cand, cnts);
    k_final<<<B, 256, 0, stream>>>(cand, cnts, score, delta, img, out);
}

// Round 15
// 116.423 us; speedup vs baseline: 1.5625x; 1.2183x over previous
//
#include <hip/hip_runtime.h>
#include <math.h>

// Problem constants (reference setup_inputs: B=32, H=80, W=120, A=9)
#define NA     9
#define HH     80
#define WWID   120
#define HWSZ   (HH * WWID)        // 9600
#define NANC   (HWSZ * NA)        // 86400 anchors per image
#define NANC4  (NANC / 4)         // 21600 float4 groups
#define PRE_NMS 100
#define NMS_THRESH 0.3f
#define MIN_SIZE 8.0f
#define STRIDE_F 16.0f
#define NCH    22                 // chunks of 1024 float4-groups (22*1024 >= 21600)
#define SLOTS  46                 // per-(batch,chunk) candidate slots
#define NFAST  (NCH * SLOTS)      // 1012 (fast-path slot count)
#define NBIN   4096               // fallback histogram bins
#define CAPF   2048               // fallback candidate cap (matches prior rounds)
// Fast-path threshold: scores >= 2.75f. ord(2.75f)=0x40300000|0x80000000.
// N(0,1): p=0.00298 -> ~257 cand/batch (need>=100), ~11.7/chunk (SLOTS=46 is
// 10 sigma). Both conditions VERIFIED at runtime in k_final; exact in-block
// fallback if violated, so correctness never depends on the distribution.
#define T0ORD  0xC0300000u

// Anchor geometry: all 9 anchors share center (8,8); widths/heights exact
// (verified against _generate_anchors(16,(0.5,1,2),(8,16,32))).
__constant__ float c_aw[NA] = {184.f, 368.f, 736.f, 128.f, 256.f, 512.f,  88.f, 176.f, 352.f};
__constant__ float c_ah[NA] = { 96.f, 192.f, 384.f, 128.f, 256.f, 512.f, 176.f, 352.f, 704.f};

// ---------------------------------------------------------------- decode ----
__device__ inline void decode_box(int n, float4 d, float imgW, float imgH,
                                  float& x1, float& y1, float& x2, float& y2) {
    int a = n % NA;
    int s = n / NA;
    int yy = s / WWID;
    int xx = s - yy * WWID;
    float aw = c_aw[a], ah = c_ah[a];
    float acx = 8.0f + STRIDE_F * (float)xx;
    float acy = 8.0f + STRIDE_F * (float)yy;
    float pcx = d.x * aw + acx;
    float pcy = d.y * ah + acy;
    float pw  = expf(d.z) * aw;
    float ph  = expf(d.w) * ah;
    x1 = pcx - 0.5f * pw;
    y1 = pcy - 0.5f * ph;
    x2 = pcx + 0.5f * pw;
    y2 = pcy + 0.5f * ph;
    float mx = imgW - 1.0f, my = imgH - 1.0f;
    x1 = fminf(fmaxf(x1, 0.0f), mx);
    x2 = fminf(fmaxf(x2, 0.0f), mx);
    y1 = fminf(fmaxf(y1, 0.0f), my);
    y2 = fminf(fmaxf(y2, 0.0f), my);
}

// order-preserving uint mapping (monotonic for all floats incl +-inf)
__device__ inline unsigned int f32_ord(float v) {
    unsigned int u = __float_as_uint(v);
    return (u & 0x80000000u) ? ~u : (u | 0x80000000u);
}
__device__ inline float ord_f32(unsigned int ov) {
    unsigned int u = (ov & 0x80000000u) ? (ov ^ 0x80000000u) : ~ov;
    return __uint_as_float(u);
}

// batch-0 min-size mask, recomputed inline (delta0 is 1.4MB -> L2-resident)
__device__ inline bool keep_mask(int n, const float4* __restrict__ d0,
                                 float imgW, float imgH) {
    float x1, y1, x2, y2;
    decode_box(n, d0[n], imgW, imgH, x1, y1, x2, y2);
    return (x2 - x1 + 1.0f >= MIN_SIZE) && (y2 - y1 + 1.0f >= MIN_SIZE);
}

// ---- K1: static-threshold compact into per-block private slot regions -----
// (unchanged from round 14 — invisible in profile, <42us incl. all replays)
__global__ __launch_bounds__(256)
void k_compact(const float* __restrict__ score,
               const float* __restrict__ delta,
               const float* __restrict__ img,
               unsigned long long* __restrict__ cand,
               unsigned int* __restrict__ cnts) {
    __shared__ unsigned int lcnt;
    int chunk = blockIdx.x, b = blockIdx.y, tid = threadIdx.x;
    if (tid == 0) lcnt = 0u;
    __syncthreads();

    const float4* fg = reinterpret_cast<const float4*>(
        score + (size_t)b * (2 * NA * HWSZ) + (size_t)NA * HWSZ);
    const float4* d0 = reinterpret_cast<const float4*>(delta);  // batch 0
    float imgH = img[0], imgW = img[1];
    unsigned long long* myc = cand + ((size_t)b * NCH + chunk) * SLOTS;

    #pragma unroll
    for (int it = 0; it < 4; ++it) {
        int q = chunk * 1024 + it * 256 + tid;
        if (q < NANC4) {
            float4 v = fg[q];
            float vv[4] = {v.x, v.y, v.z, v.w};
            #pragma unroll
            for (int c = 0; c < 4; ++c) {
                unsigned ov = f32_ord(vv[c]);
                if (ov >= T0ORD) {                    // ~0.3% of elements
                    int m = 4 * q + c;                // score order a*HWSZ+s
                    int a = m / HWSZ;
                    int s = m - a * HWSZ;
                    int n = s * NA + a;               // anchor order (top_k idx)
                    if (keep_mask(n, d0, imgW, imgH)) {
                        unsigned slot = atomicAdd(&lcnt, 1u);
                        if (slot < SLOTS)
                            myc[slot] = ((unsigned long long)ov << 32) |
                                        (unsigned long long)(0xFFFFFFFFu - (unsigned)n);
                    }
                }
            }
        }
    }
    __syncthreads();
    unsigned cnt = lcnt;
    if (tid == 0) cnts[b * NCH + chunk] = cnt;        // true count (may exceed SLOTS)
    for (unsigned l = cnt + tid; l < SLOTS; l += 256) myc[l] = 0ull;  // zero-pad
}

// generic in-LDS bitonic sort, descending, S = power of 2 (block-uniform).
// With nthr=1024 and S<=1024 each step is ONE compare-exchange per thread --
// no serialized aliasing chain (the round-14 75us lesson).
__device__ inline void bitonic_desc(unsigned long long* sh, int S, int nthr) {
    for (int k = 2; k <= S; k <<= 1) {
        for (int j = k >> 1; j > 0; j >>= 1) {
            for (int i = threadIdx.x; i < S; i += nthr) {
                int ix = i ^ j;
                if (ix > i) {
                    unsigned long long va = sh[i], vb = sh[ix];
                    bool up = ((i & k) == 0);
                    bool sw = up ? (va < vb) : (va > vb);
                    if (sw) { sh[i] = vb; sh[ix] = va; }
                }
            }
            __syncthreads();
        }
    }
}

// ---- K2: verify fast path, compact-by-counts, sort, top-100, NMS, write ---
__global__ __launch_bounds__(1024)
void k_final(const unsigned long long* __restrict__ cand,
             const unsigned int* __restrict__ cnts,
             const float* __restrict__ score,
             const float* __restrict__ delta,
             const float* __restrict__ img,
             float* __restrict__ out) {
    __shared__ unsigned long long sh[CAPF];          // 16KB; aliased in fallback
    __shared__ unsigned int lcnts[NCH];
    __shared__ float bx1[PRE_NMS], by1[PRE_NMS], bx2[PRE_NMS], by2[PRE_NMS];
    __shared__ float bsc[PRE_NMS], barea[PRE_NMS];
    __shared__ unsigned int supW[PRE_NMS * 4];
    __shared__ unsigned int keepW[4];
    __shared__ int osrc[PRE_NMS];
    __shared__ unsigned int part[256];
    __shared__ int best;
    __shared__ unsigned int scnt;

    int b = blockIdx.x, tid = threadIdx.x;
    float imgH = img[0], imgW = img[1];
    const float4* fg = reinterpret_cast<const float4*>(
        score + (size_t)b * (2 * NA * HWSZ) + (size_t)NA * HWSZ);
    const float4* d0 = reinterpret_cast<const float4*>(delta);  // batch 0 (mask)

    if (tid < NCH) lcnts[tid] = cnts[b * NCH + tid];
    __syncthreads();

    // fast-path validity (uniform: all threads compute same total/over)
    unsigned total = 0; bool over = false;
    for (int c = 0; c < NCH; ++c) {
        unsigned cc = lcnts[c];
        total += cc;
        over = over || (cc > SLOTS);
    }
    bool fast = (!over) && (total >= PRE_NMS);

    int S;
    if (fast) {
        // compact-by-counts: chunk c's real entries are slots [0,cnt_c) --
        // scatter them contiguous, sort only next-pow2(total) (~512 typical).
        S = 128;
        while (S < (int)total) S <<= 1;
        for (int l = tid; l < S; l += 1024) sh[l] = 0ull;
        __syncthreads();
        if (tid < NFAST) {
            int c  = tid / SLOTS;
            int sl = tid - c * SLOTS;
            unsigned cc = lcnts[c];
            if ((unsigned)sl < cc) {
                unsigned pre = 0;
                #pragma unroll
                for (int k2 = 0; k2 < NCH; ++k2)
                    if (k2 < c) pre += lcnts[k2];
                sh[pre + sl] = cand[((size_t)b * NCH + c) * SLOTS + sl];
            }
        }
        __syncthreads();
    } else {
        // exact fallback (never taken for the benchmark input): in-block
        // 4096-bin histogram -> threshold bin T -> recollect (validated math)
        unsigned int* lh = reinterpret_cast<unsigned int*>(sh);  // 4096 bins
        for (int i = tid; i < NBIN; i += 1024) lh[i] = 0u;
        if (tid == 0) best = 0;
        __syncthreads();
        for (int q = tid; q < NANC4; q += 1024) {
            float4 v = fg[q];
            float vv[4] = {v.x, v.y, v.z, v.w};
            #pragma unroll
            for (int c = 0; c < 4; ++c) {
                int m = 4 * q + c;
                int a = m / HWSZ;
                int s = m - a * HWSZ;
                int n = s * NA + a;
                float av = keep_mask(n, d0, imgW, imgH) ? vv[c] : -INFINITY;
                atomicAdd(&lh[f32_ord(av) >> 20], 1u);
            }
        }
        __syncthreads();
        unsigned g[16]; unsigned ssum = 0;
        if (tid < 256) {
            #pragma unroll
            for (int j = 0; j < 16; ++j) { g[j] = lh[tid * 16 + j]; ssum += g[j]; }
            part[tid] = ssum;
        }
        __syncthreads();
        for (int off = 1; off < 256; off <<= 1) {
            unsigned v = 0;
            if (tid < 256 && tid + off < 256) v = part[tid + off];
            __syncthreads();
            if (tid < 256) part[tid] += v;
            __syncthreads();
        }
        if (tid < 256) {
            unsigned cum = (tid + 1 < 256) ? part[tid + 1] : 0u;
            int loc = -1;
            #pragma unroll
            for (int j = 15; j >= 0; --j) {
                cum += g[j];
                if (cum >= PRE_NMS) { loc = tid * 16 + j; break; }
            }
            if (loc >= 0) atomicMax(&best, loc);
        }
        __syncthreads();
        unsigned T = (unsigned)best;
        if (tid == 0) scnt = 0u;
        __syncthreads();
        for (int l = tid; l < CAPF; l += 1024) sh[l] = 0ull;  // overwrites lh
        __syncthreads();
        for (int q = tid; q < NANC4; q += 1024) {
            float4 v = fg[q];
            float vv[4] = {v.x, v.y, v.z, v.w};
            #pragma unroll
            for (int c = 0; c < 4; ++c) {
                int m = 4 * q + c;
                int a = m / HWSZ;
                int s = m - a * HWSZ;
                int n = s * NA + a;
                float av = keep_mask(n, d0, imgW, imgH) ? vv[c] : -INFINITY;
                unsigned ov = f32_ord(av);
                if ((ov >> 20) >= T) {
                    unsigned slot = atomicAdd(&scnt, 1u);
                    if (slot < CAPF)
                        sh[slot] = ((unsigned long long)ov << 32) |
                                   (unsigned long long)(0xFFFFFFFFu - (unsigned)n);
                }
            }
        }
        S = CAPF;
    }
    if (tid < 4) keepW[tid] = 0u;
    for (int i = tid; i < PRE_NMS * 4; i += 1024) supW[i] = 0u;
    __syncthreads();

    bitonic_desc(sh, S, 1024);   // ends with __syncthreads

    // ---------------- validated tail (logic unchanged since round 9) -------
    if (tid < PRE_NMS) {
        unsigned long long key = sh[tid];
        float x1 = 0.f, y1 = 0.f, x2 = 0.f, y2 = 0.f, v = -INFINITY, ar = 1.f;
        if (key != 0ull) {   // real candidate (pad keys are exactly 0)
            unsigned n = 0xFFFFFFFFu - (unsigned)(key & 0xFFFFFFFFu);
            v = ord_f32((unsigned)(key >> 32));
            float4 d = reinterpret_cast<const float4*>(
                delta + (size_t)b * (4 * NANC))[n];
            decode_box((int)n, d, imgW, imgH, x1, y1, x2, y2);
            ar = (x2 - x1 + 1.0f) * (y2 - y1 + 1.0f);
        }
        bx1[tid] = x1; by1[tid] = y1; bx2[tid] = x2; by2[tid] = y2;
        bsc[tid] = v;  barea[tid] = ar;
        if (key != 0ull && isfinite(v))
            atomicOr(&keepW[tid >> 5], 1u << (tid & 31));
    }
    __syncthreads();

    for (int p = tid; p < PRE_NMS * PRE_NMS; p += 1024) {
        int i = p / PRE_NMS;
        int j = p - i * PRE_NMS;
        if (j > i) {
            float ix1 = fmaxf(bx1[i], bx1[j]);
            float iy1 = fmaxf(by1[i], by1[j]);
            float ix2 = fminf(bx2[i], bx2[j]);
            float iy2 = fminf(by2[i], by2[j]);
            float iw = fmaxf(ix2 - ix1 + 1.0f, 0.0f);
            float ih = fmaxf(iy2 - iy1 + 1.0f, 0.0f);
            float inter = iw * ih;
            float iou = inter / (barea[i] + barea[j] - inter);
            if (iou > NMS_THRESH)
                atomicOr(&supW[i * 4 + (j >> 5)], 1u << (j & 31));
        }
    }
    __syncthreads();

    // greedy pass entirely in wave-0 registers (no barriers)
    if (tid < 64) {
        unsigned r0w0 = supW[tid * 4 + 0], r0w1 = supW[tid * 4 + 1];
        unsigned r0w2 = supW[tid * 4 + 2], r0w3 = supW[tid * 4 + 3];
        unsigned r1w0 = 0, r1w1 = 0, r1w2 = 0, r1w3 = 0;
        if (tid < PRE_NMS - 64) {
            r1w0 = supW[(64 + tid) * 4 + 0]; r1w1 = supW[(64 + tid) * 4 + 1];
            r1w2 = supW[(64 + tid) * 4 + 2]; r1w3 = supW[(64 + tid) * 4 + 3];
        }
        unsigned kw0 = keepW[0], kw1 = keepW[1], kw2 = keepW[2], kw3 = keepW[3];
        #pragma unroll
        for (int i = 0; i < PRE_NMS - 1; ++i) {
            unsigned kword = (i < 32) ? kw0 : (i < 64) ? kw1 : (i < 96) ? kw2 : kw3;
            if ((kword >> (i & 31)) & 1u) {   // uniform across the wave
                unsigned s0, s1, s2, s3;
                if (i < 64) {
                    s0 = __shfl(r0w0, i, 64); s1 = __shfl(r0w1, i, 64);
                    s2 = __shfl(r0w2, i, 64); s3 = __shfl(r0w3, i, 64);
                } else {
                    s0 = __shfl(r1w0, i - 64, 64); s1 = __shfl(r1w1, i - 64, 64);
                    s2 = __shfl(r1w2, i - 64, 64); s3 = __shfl(r1w3, i - 64, 64);
                }
                kw0 &= ~s0; kw1 &= ~s1; kw2 &= ~s2; kw3 &= ~s3;
            }
        }
        if (tid == 0) { keepW[0] = kw0; keepW[1] = kw1; keepW[2] = kw2; keepW[3] = kw3; }
    }
    __syncthreads();

    if (tid < PRE_NMS) osrc[tid] = -1;
    __syncthreads();
    if (tid < PRE_NMS) {
        unsigned k0 = keepW[0], k1 = keepW[1], k2 = keepW[2], k3 = keepW[3];
        int w = tid >> 5, bit = tid & 31;
        unsigned kword = (w == 0) ? k0 : (w == 1) ? k1 : (w == 2) ? k2 : k3;
        if ((kword >> bit) & 1u) {
            int pos = __popc(kword & ((1u << bit) - 1u));
            if (w > 0) pos += __popc(k0);
            if (w > 1) pos += __popc(k1);
            if (w > 2) pos += __popc(k2);
            osrc[pos] = tid;
        }
    }
    __syncthreads();

    float* ob = out + (size_t)b * (PRE_NMS * 5);
    if (tid < PRE_NMS) {
        int j = osrc[tid];
        float r0 = 0.f, r1 = 0.f, r2 = 0.f, r3 = 0.f, r4 = 0.f;
        if (j >= 0) { r0 = bx1[j]; r1 = by1[j]; r2 = bx2[j]; r3 = by2[j]; r4 = bsc[j]; }
        ob[tid * 5 + 0] = r0;
        ob[tid * 5 + 1] = r1;
        ob[tid * 5 + 2] = r2;
        ob[tid * 5 + 3] = r3;
        ob[tid * 5 + 4] = r4;
    }
}

// ----------------------------------------------------------------- launch ---
extern "C" void kernel_launch(void* const* d_in, const int* in_sizes, int n_in,
                              void* d_out, int out_size, void* d_ws, size_t ws_size,
                              hipStream_t stream) {
    const float* score = (const float*)d_in[0];
    const float* delta = (const float*)d_in[1];
    const float* img   = (const float*)d_in[2];
    float* out = (float*)d_out;

    int B = in_sizes[0] / (2 * NA * HWSZ);   // 32 for the reference shapes

    // ws layout: [cand: B*NCH*SLOTS u64][cnts: B*NCH u32]  (~262KB total)
    // Every consumed word is written this call (slots zero-padded, cnts
    // unconditional) -> no zeroing kernel, safe under 0xAA re-poison.
    unsigned long long* cand = (unsigned long long*)d_ws;
    unsigned int* cnts = (unsigned int*)((char*)d_ws +
                          (size_t)B * NCH * SLOTS * sizeof(unsigned long long));

    dim3 g1(NCH, B);
    k_compact<<<g1, 256, 0, stream>>>(score, delta, img, cand, cnts);
    k_final<<<B, 1024, 0, stream>>>(cand, cnts, score, delta, img, out);
}